// Round 1
// baseline (118.241 us; speedup 1.0000x reference)
//
#include <hip/hip_runtime.h>

// SoftNCutsLoss on MI355X.
// batch: (4,1,32,32,32) f32, preds: (4,8,32,32,32) f32 -> out: (4,) f32
//
// Structure: per-voxel accumulation over 251 valid offsets of the 7^3 window.
// Block = 4x4x8 voxel tile (128 threads), halo 10x10x14 staged in LDS.
// Preds tile stored as two float4 arrays (k0-3, k4-7) -> conflict-free ds_read_b128
// (quad index = vox mod 8, consecutive lanes cover all 8 bank quads).
// Deterministic 2-stage reduction through d_ws (no atomics).

#define EPS_F 2.220446049250313e-16f

constexpr int TD = 4, TH = 4, TW = 8;      // tile dims (d,h,w)
constexpr int HD = 10, HH = 10, HW = 14;   // halo dims (+3 each side)
constexpr int HVOL = HD * HH * HW;         // 1400
constexpr int NT = 128;                    // threads per block
constexpr int NBLK = 1024;                 // 4 batches * 256 tiles

// exp(-s^2/16) for s^2 in {0,1,4,9}
#define EX0 1.0f
#define EX1 0.93941306281347578611f
#define EX4 0.77880078307140486825f
#define EX9 0.56978282473092302544f

__global__ __launch_bounds__(NT, 2)
void softncuts_main(const float* __restrict__ batch,
                    const float* __restrict__ preds,
                    float* __restrict__ partials) {
    __shared__ float  sB[HVOL];        // batch halo tile
    __shared__ float4 sP0[HVOL];       // preds k=0..3
    __shared__ float4 sP1[HVOL];       // preds k=4..7
    __shared__ float  sRed[2][16];

    const int bid  = blockIdx.x;
    const int bb   = bid >> 8;          // batch index 0..3
    const int tile = bid & 255;
    const int tw = tile & 3;            // 0..3  -> w0 = tw*8
    const int th = (tile >> 2) & 7;     // 0..7  -> h0 = th*4
    const int td = tile >> 5;           // 0..7  -> d0 = td*4
    const int d0 = td * TD, h0 = th * TH, w0 = tw * TW;

    const int tid = threadIdx.x;
    const int lw = tid & 7;             // 0..7
    const int lh = (tid >> 3) & 3;      // 0..3
    const int ld = tid >> 5;            // 0..3

    // ---- stage halo tile (OOB -> EPS, matching ConstantPad3d(radius-1, eps)) ----
    const float* bbase = batch + (size_t)bb * 32768;
    const float* pbase = preds + (size_t)bb * 8 * 32768;
    for (int v = tid; v < HVOL; v += NT) {
        int hw_ = v % HW;
        int t   = v / HW;
        int hh_ = t % HH;
        int hd_ = t / HH;
        int gd = d0 + hd_ - 3, gh = h0 + hh_ - 3, gw = w0 + hw_ - 3;
        bool in = ((unsigned)gd < 32u) & ((unsigned)gh < 32u) & ((unsigned)gw < 32u);
        float bv = EPS_F;
        float4 p0 = make_float4(EPS_F, EPS_F, EPS_F, EPS_F);
        float4 p1 = p0;
        if (in) {
            int sidx = (gd * 32 + gh) * 32 + gw;
            bv = bbase[sidx];
            const float* pp = pbase + sidx;
            p0.x = pp[0 * 32768]; p0.y = pp[1 * 32768];
            p0.z = pp[2 * 32768]; p0.w = pp[3 * 32768];
            p1.x = pp[4 * 32768]; p1.y = pp[5 * 32768];
            p1.z = pp[6 * 32768]; p1.w = pp[7 * 32768];
        }
        sB[v] = bv;
        sP0[v] = p0;
        sP1[v] = p1;
    }
    __syncthreads();

    // ---- main accumulation over window offsets ----
    const int vown = ((ld + 3) * HH + (lh + 3)) * HW + (lw + 3);
    const float b_own = sB[vown];

    float n0 = 0.f, n1 = 0.f, n2 = 0.f, n3 = 0.f;
    float n4 = 0.f, n5 = 0.f, n6 = 0.f, n7 = 0.f;
    float sumw = 0.f;

    for (int dxi = 0; dxi < 7; ++dxi) {
        const int dx  = dxi - 3;
        const int dxx = dx * dx;                       // runtime, wave-uniform
        const float wdx = __expf((float)dxx * -0.0625f);
        const int vbase_d = (ld + dxi) * HH;
#pragma unroll
        for (int dyi = 0; dyi < 7; ++dyi) {
            const int dy  = dyi - 3;
            const int c2y = dy * dy;                   // compile-time
            constexpr float EXT[10] = {EX0, EX1, 0.f, 0.f, EX4,
                                       0.f, 0.f, 0.f, 0.f, EX9};
            const int vrow = (vbase_d + lh + dyi) * HW + lw;
#pragma unroll
            for (int dzi = 0; dzi < 7; ++dzi) {
                const int dz = dzi - 3;
                const int c2 = c2y + dz * dz;          // compile-time
                if (c2 >= 16) continue;                // folded at compile time
                if (dxx + c2 >= 16) continue;          // uniform scalar branch
                const float wyz = EXT[c2y] * EXT[dz * dz];  // literal
                const int v = vrow + dzi;
                const float sb = sB[v];
                const float4 p0 = sP0[v];
                const float4 p1 = sP1[v];
                const float d = b_own - sb;
                const float aff = __expf(d * d * -0.01f) * (wdx * wyz);
                sumw += aff;
                n0 += aff * p0.x; n1 += aff * p0.y;
                n2 += aff * p0.z; n3 += aff * p0.w;
                n4 += aff * p1.x; n5 += aff * p1.y;
                n6 += aff * p1.z; n7 += aff * p1.w;
            }
        }
    }

    // ---- per-block partial assocA / assocV ----
    const float4 q0 = sP0[vown];
    const float4 q1 = sP1[vown];
    float vals[16];
    vals[0] = n0 * q0.x; vals[1] = n1 * q0.y; vals[2] = n2 * q0.z; vals[3] = n3 * q0.w;
    vals[4] = n4 * q1.x; vals[5] = n5 * q1.y; vals[6] = n6 * q1.z; vals[7] = n7 * q1.w;
    vals[8]  = sumw * q0.x; vals[9]  = sumw * q0.y;
    vals[10] = sumw * q0.z; vals[11] = sumw * q0.w;
    vals[12] = sumw * q1.x; vals[13] = sumw * q1.y;
    vals[14] = sumw * q1.z; vals[15] = sumw * q1.w;

#pragma unroll
    for (int i = 0; i < 16; ++i) {
        float s = vals[i];
        for (int off = 32; off; off >>= 1) s += __shfl_down(s, off);
        vals[i] = s;
    }
    const int wave = tid >> 6;
    const int lane = tid & 63;
    if (lane == 0) {
#pragma unroll
        for (int i = 0; i < 16; ++i) sRed[wave][i] = vals[i];
    }
    __syncthreads();
    if (tid < 16) {
        partials[bid * 16 + tid] = sRed[0][tid] + sRed[1][tid];
    }
}

__global__ __launch_bounds__(1024)
void softncuts_finalize(const float* __restrict__ partials,
                        float* __restrict__ out) {
    __shared__ float red[64];
    const int tid = threadIdx.x;          // 0..1023
    const int target = tid >> 4;          // 0..63 : b = target>>4, v = target&15
    const int j0 = tid & 15;
    const int b = target >> 4;
    const int v = target & 15;

    float s = 0.f;
    for (int j = j0; j < 256; j += 16)
        s += partials[((b << 8) + j) * 16 + v];
    for (int off = 8; off; off >>= 1) s += __shfl_down(s, off, 16);
    if (j0 == 0) red[target] = s;
    __syncthreads();

    if (tid < 4) {
        float acc = 0.f;
#pragma unroll
        for (int k = 0; k < 8; ++k)
            acc += red[tid * 16 + k] / red[tid * 16 + 8 + k];
        out[tid] = 8.0f - acc;
    }
}

extern "C" void kernel_launch(void* const* d_in, const int* in_sizes, int n_in,
                              void* d_out, int out_size, void* d_ws, size_t ws_size,
                              hipStream_t stream) {
    const float* batch = (const float*)d_in[0];
    const float* preds = (const float*)d_in[1];
    float* out      = (float*)d_out;
    float* partials = (float*)d_ws;   // NBLK*16 floats = 64 KB

    softncuts_main<<<dim3(NBLK), dim3(NT), 0, stream>>>(batch, preds, partials);
    softncuts_finalize<<<dim3(1), dim3(1024), 0, stream>>>(partials, out);
}

// Round 2
// 109.393 us; speedup vs baseline: 1.0809x; 1.0809x over previous
//
#include <hip/hip_runtime.h>

// SoftNCutsLoss on MI355X — R2.
// batch: (4,1,32,32,32) f32, preds: (4,8,32,32,32) f32 -> out: (4,) f32
//
// R2 changes vs R1 (theory: 9.29M LDS bank-conflict cycles from float4 ds_read_b128;
// occupancy 10.6% from 8 waves/CU):
//  - preds LDS layout: two float4 arrays -> 8 scalar float planes (ds_read_b32,
//    lane-stride-1 = max 2-way bank aliasing = free).
//  - 256-thread blocks: waves 0-1 handle dy in {-3,-1,1,3}, waves 2-3 handle
//    dy in {-2,0,2} for the same 128-voxel tile (offset-split; sums are linear).
//  - partials transposed to [16][NBLK] for coalesced finalize reads.

#define EPS_F 2.220446049250313e-16f

constexpr int TD = 4, TH = 4, TW = 8;      // tile dims (d,h,w)
constexpr int HD = 10, HH = 10, HW = 14;   // halo dims (+3 each side)
constexpr int HVOL = HD * HH * HW;         // 1400
constexpr int NT = 256;                    // threads per block (4 waves)
constexpr int NBLK = 1024;                 // 4 batches * 256 tiles

// exp(-s^2/16) for s^2 in {0,1,4,9}
#define EX0 1.0f
#define EX1 0.93941306281347578611f
#define EX4 0.77880078307140486825f
#define EX9 0.56978282473092302544f

__device__ __constant__ float EXT_C[10] = {EX0, EX1, 0.f, 0.f, EX4,
                                           0.f, 0.f, 0.f, 0.f, EX9};

template <int HALF>
__device__ __forceinline__ void accum_offsets(const float* __restrict__ sB,
                                              const float* __restrict__ sP,
                                              int vown, float b_own,
                                              float acc[9]) {
    constexpr float EXT[10] = {EX0, EX1, 0.f, 0.f, EX4, 0.f, 0.f, 0.f, 0.f, EX9};
    constexpr int NDY = HALF ? 3 : 4;
    constexpr int DYI[4] = {HALF ? 1 : 0, HALF ? 3 : 2, HALF ? 5 : 4, HALF ? 7 : 6};

    for (int dxi = 0; dxi < 7; ++dxi) {
        const int dx  = dxi - 3;
        const int dxx = dx * dx;                         // runtime, wave-uniform
        const float wdx = __expf((float)dxx * -0.0625f);
        const int base = vown + (dxi - 3) * (HH * HW);   // depth shift
#pragma unroll
        for (int yy = 0; yy < NDY; ++yy) {
            const int dyi = DYI[yy];                     // constant after unroll
            const int dy  = dyi - 3;
            const int c2y = dy * dy;
#pragma unroll
            for (int dzi = 0; dzi < 7; ++dzi) {
                const int dz = dzi - 3;
                const int c2 = c2y + dz * dz;            // compile-time
                if (c2 >= 16) continue;                  // folded at compile time
                if (dxx + c2 >= 16) continue;            // uniform scalar branch
                const float wyz = EXT[c2y] * EXT[dz * dz];
                const int nv = base + dy * HW + dz;
                const float sb = sB[nv];
                const float d = b_own - sb;
                const float aff = __expf(d * d * -0.01f) * (wdx * wyz);
                acc[8] += aff;
#pragma unroll
                for (int k = 0; k < 8; ++k)
                    acc[k] += aff * sP[k * HVOL + nv];
            }
        }
    }
}

__global__ __launch_bounds__(NT, 3)
void softncuts_main(const float* __restrict__ batch,
                    const float* __restrict__ preds,
                    float* __restrict__ partials) {
    __shared__ float sB[HVOL];          // batch halo tile
    __shared__ float sP[8 * HVOL];      // preds halo planes, SoA
    __shared__ float sRed[4][16];

    const int bid  = blockIdx.x;
    const int bb   = bid >> 8;          // batch index 0..3
    const int tile = bid & 255;
    const int tw = tile & 3;            // 0..3  -> w0 = tw*8
    const int th = (tile >> 2) & 7;     // 0..7  -> h0 = th*4
    const int td = tile >> 5;           // 0..7  -> d0 = td*4
    const int d0 = td * TD, h0 = th * TH, w0 = tw * TW;

    const int tid  = threadIdx.x;
    const int half = tid >> 7;          // wave-uniform (waves 0,1 vs 2,3)
    const int vtid = tid & 127;
    const int lw = vtid & 7;            // 0..7
    const int lh = (vtid >> 3) & 3;     // 0..3
    const int ld = vtid >> 5;           // 0..3

    // ---- stage halo tile (OOB -> EPS, matching ConstantPad3d(radius-1, eps)) ----
    const float* bbase = batch + (size_t)bb * 32768;
    const float* pbase = preds + (size_t)bb * 8 * 32768;
    for (int v = tid; v < HVOL; v += NT) {
        int hw_ = v % HW;
        int t   = v / HW;
        int hh_ = t % HH;
        int hd_ = t / HH;
        int gd = d0 + hd_ - 3, gh = h0 + hh_ - 3, gw = w0 + hw_ - 3;
        bool in = ((unsigned)gd < 32u) & ((unsigned)gh < 32u) & ((unsigned)gw < 32u);
        int sidx = (gd * 32 + gh) * 32 + gw;
        sB[v] = in ? bbase[sidx] : EPS_F;
#pragma unroll
        for (int k = 0; k < 8; ++k)
            sP[k * HVOL + v] = in ? pbase[sidx + k * 32768] : EPS_F;
    }
    __syncthreads();

    // ---- main accumulation over this half's window offsets ----
    const int vown = ((ld + 3) * HH + (lh + 3)) * HW + (lw + 3);
    const float b_own = sB[vown];

    float acc[9];
#pragma unroll
    for (int i = 0; i < 9; ++i) acc[i] = 0.f;

    if (half == 0) accum_offsets<0>(sB, sP, vown, b_own, acc);
    else           accum_offsets<1>(sB, sP, vown, b_own, acc);

    // ---- per-block partial assocA / assocV ----
    float q[8];
#pragma unroll
    for (int k = 0; k < 8; ++k) q[k] = sP[k * HVOL + vown];

    float vals[16];
#pragma unroll
    for (int k = 0; k < 8; ++k) {
        vals[k]     = acc[k] * q[k];
        vals[8 + k] = acc[8] * q[k];
    }

#pragma unroll
    for (int i = 0; i < 16; ++i) {
        float s = vals[i];
        for (int off = 32; off; off >>= 1) s += __shfl_down(s, off);
        vals[i] = s;
    }
    const int wave = tid >> 6;
    const int lane = tid & 63;
    if (lane == 0) {
#pragma unroll
        for (int i = 0; i < 16; ++i) sRed[wave][i] = vals[i];
    }
    __syncthreads();
    if (tid < 16) {
        partials[tid * NBLK + bid] =
            sRed[0][tid] + sRed[1][tid] + sRed[2][tid] + sRed[3][tid];
    }
}

__global__ __launch_bounds__(1024)
void softncuts_finalize(const float* __restrict__ partials,
                        float* __restrict__ out) {
    __shared__ float red[64];
    const int tid = threadIdx.x;          // 0..1023
    const int group = tid >> 4;           // 0..63 = bb*16 + slot
    const int j0 = tid & 15;
    const int slot = group & 15;
    const int bb = group >> 4;

    const float* p = partials + slot * NBLK + bb * 256;
    float s = 0.f;
#pragma unroll
    for (int k = 0; k < 16; ++k) s += p[j0 + 16 * k];
    for (int off = 8; off; off >>= 1) s += __shfl_down(s, off, 16);
    if (j0 == 0) red[group] = s;
    __syncthreads();

    if (tid < 4) {
        float accv = 0.f;
#pragma unroll
        for (int k = 0; k < 8; ++k)
            accv += red[tid * 16 + k] / red[tid * 16 + 8 + k];
        out[tid] = 8.0f - accv;
    }
}

extern "C" void kernel_launch(void* const* d_in, const int* in_sizes, int n_in,
                              void* d_out, int out_size, void* d_ws, size_t ws_size,
                              hipStream_t stream) {
    const float* batch = (const float*)d_in[0];
    const float* preds = (const float*)d_in[1];
    float* out      = (float*)d_out;
    float* partials = (float*)d_ws;   // 16*NBLK floats = 64 KB

    softncuts_main<<<dim3(NBLK), dim3(NT), 0, stream>>>(batch, preds, partials);
    softncuts_finalize<<<dim3(1), dim3(1024), 0, stream>>>(partials, out);
}